// Round 3
// baseline (826.584 us; speedup 1.0000x reference)
//
#include <hip/hip_runtime.h>

#define N_TOK 262144
#define DIM 64
#define K_CODES 1024
#define OUT_LOSS_OFF (N_TOK * DIM)      // 16777216
#define OUT_IDX_OFF (N_TOK * DIM + 1)   // 16777217

// Emulates np.sum(x**2) for 64 contiguous fp32 values: numpy pairwise
// summation (8 accumulators, unroll-8, then paired combine). Squares are
// individually rounded (contract OFF prevents x*x+r -> fma fusion).
__device__ __forceinline__ float np_sumsq64(const float* x) {
#pragma clang fp contract(off)
  float r[8];
#pragma unroll
  for (int j = 0; j < 8; ++j) r[j] = x[j] * x[j];
#pragma unroll
  for (int i = 8; i < 64; i += 8) {
#pragma unroll
    for (int j = 0; j < 8; ++j) r[j] += x[i + j] * x[i + j];
  }
  return ((r[0] + r[1]) + (r[2] + r[3])) + ((r[4] + r[5]) + (r[6] + r[7]));
}

// ---------------- main: one thread per token ----------------
__global__ __launch_bounds__(256) void vq_main_k(
    const float* __restrict__ z, const float* __restrict__ w,
    float* __restrict__ out, double* __restrict__ loss_acc) {
#pragma clang fp contract(off)
  __shared__ float s_w2[K_CODES];
  __shared__ double red[4];

  // Block-cooperative ||w_c||^2 into LDS, numpy-pairwise bit-exact.
  for (int c0 = 0; c0 < K_CODES; c0 += 256) {
    int c = c0 + (int)threadIdx.x;
    float wl[DIM];
    const float4* wp = (const float4*)(w + (size_t)c * DIM);
#pragma unroll
    for (int i = 0; i < 16; ++i) {
      float4 v = wp[i];
      wl[4 * i + 0] = v.x;
      wl[4 * i + 1] = v.y;
      wl[4 * i + 2] = v.z;
      wl[4 * i + 3] = v.w;
    }
    s_w2[c] = np_sumsq64(wl);
  }
  __syncthreads();

  const int t = blockIdx.x * 256 + (int)threadIdx.x;

  // zs = 2*z resident in 64 VGPRs (doubling is exact; BLAS computed (2z)@wT).
  float zs[DIM];
  {
    const float4* zp = (const float4*)(z + (size_t)t * DIM);
#pragma unroll
    for (int i = 0; i < 16; ++i) {
      float4 v = zp[i];
      zs[4 * i + 0] = v.x + v.x;
      zs[4 * i + 1] = v.y + v.y;
      zs[4 * i + 2] = v.z + v.z;
      zs[4 * i + 3] = v.w + v.w;
    }
  }

  // ||z||^2, numpy-pairwise bit-exact (recover z = 0.5*zs exactly).
  float s_z2;
  {
    float zl[DIM];
#pragma unroll
    for (int k = 0; k < DIM; ++k) zl[k] = 0.5f * zs[k];
    s_z2 = np_sumsq64(zl);
  }

  // Main loop: emulate np's dist = fl(fl(s_z2 + s_w2[c]) - dot2[c]) where
  // dot2 = sequential-k fma chain of (2z_k)*w_k (BLAS sgemm microkernel
  // order). argmin with strict '<' = numpy first-min-wins.
  float best = 3.4e38f;
  int bidx = 0;
#pragma unroll 1
  for (int c = 0; c < K_CODES; c += 4) {
    const float4* w0 = (const float4*)(w + (size_t)c * DIM);
    const float4* w1 = (const float4*)(w + (size_t)(c + 1) * DIM);
    const float4* w2 = (const float4*)(w + (size_t)(c + 2) * DIM);
    const float4* w3 = (const float4*)(w + (size_t)(c + 3) * DIM);
    float a0 = 0.f, a1 = 0.f, a2 = 0.f, a3 = 0.f;
#pragma unroll
    for (int i = 0; i < 16; ++i) {
      float4 p0 = w0[i];
      float4 p1 = w1[i];
      float4 p2 = w2[i];
      float4 p3 = w3[i];
      // strictly ascending k within each chain (4 independent chains for ILP)
      a0 = __builtin_fmaf(zs[4 * i + 0], p0.x, a0);
      a0 = __builtin_fmaf(zs[4 * i + 1], p0.y, a0);
      a0 = __builtin_fmaf(zs[4 * i + 2], p0.z, a0);
      a0 = __builtin_fmaf(zs[4 * i + 3], p0.w, a0);
      a1 = __builtin_fmaf(zs[4 * i + 0], p1.x, a1);
      a1 = __builtin_fmaf(zs[4 * i + 1], p1.y, a1);
      a1 = __builtin_fmaf(zs[4 * i + 2], p1.z, a1);
      a1 = __builtin_fmaf(zs[4 * i + 3], p1.w, a1);
      a2 = __builtin_fmaf(zs[4 * i + 0], p2.x, a2);
      a2 = __builtin_fmaf(zs[4 * i + 1], p2.y, a2);
      a2 = __builtin_fmaf(zs[4 * i + 2], p2.z, a2);
      a2 = __builtin_fmaf(zs[4 * i + 3], p2.w, a2);
      a3 = __builtin_fmaf(zs[4 * i + 0], p3.x, a3);
      a3 = __builtin_fmaf(zs[4 * i + 1], p3.y, a3);
      a3 = __builtin_fmaf(zs[4 * i + 2], p3.z, a3);
      a3 = __builtin_fmaf(zs[4 * i + 3], p3.w, a3);
    }
    float d0 = (s_z2 + s_w2[c + 0]) - a0;  // two separately-rounded fp32 adds
    float d1 = (s_z2 + s_w2[c + 1]) - a1;
    float d2 = (s_z2 + s_w2[c + 2]) - a2;
    float d3 = (s_z2 + s_w2[c + 3]) - a3;
    if (d0 < best) { best = d0; bidx = c + 0; }
    if (d1 < best) { best = d1; bidx = c + 1; }
    if (d2 < best) { best = d2; bidx = c + 2; }
    if (d3 < best) { best = d3; bidx = c + 3; }
  }

  // Epilogue: write z_q (== z_q_st numerically within fp32 threshold), index,
  // and fp64 loss from the final index.
  double ls = 0.0;
  {
    const float4* wq = (const float4*)(w + (size_t)bidx * DIM);
    float4* op = (float4*)(out + (size_t)t * DIM);
#pragma unroll
    for (int i = 0; i < 16; ++i) {
      float4 v = wq[i];
      op[i] = v;
      double d0 = (double)v.x - 0.5 * (double)zs[4 * i + 0];
      double d1 = (double)v.y - 0.5 * (double)zs[4 * i + 1];
      double d2 = (double)v.z - 0.5 * (double)zs[4 * i + 2];
      double d3 = (double)v.w - 0.5 * (double)zs[4 * i + 3];
      ls = __builtin_fma(d0, d0, ls);
      ls = __builtin_fma(d1, d1, ls);
      ls = __builtin_fma(d2, d2, ls);
      ls = __builtin_fma(d3, d3, ls);
    }
  }
  out[OUT_IDX_OFF + t] = (float)bidx;

  // loss reduce: wave shuffle -> LDS -> one atomic per block
  for (int off = 32; off > 0; off >>= 1) ls += __shfl_down(ls, off, 64);
  if ((threadIdx.x & 63) == 0) red[threadIdx.x >> 6] = ls;
  __syncthreads();
  if (threadIdx.x == 0)
    atomicAdd(loss_acc, (red[0] + red[1]) + (red[2] + red[3]));
}

// ---------------- finalize loss ----------------
__global__ void vq_final_k(const double* __restrict__ loss_acc,
                           float* __restrict__ out) {
  // loss = q_latent + 0.25 * e_latent = 1.25 * mean((z_q - z)^2)
  out[OUT_LOSS_OFF] =
      (float)(1.25 * (*loss_acc) * (1.0 / (double)((size_t)N_TOK * DIM)));
}

extern "C" void kernel_launch(void* const* d_in, const int* in_sizes, int n_in,
                              void* d_out, int out_size, void* d_ws,
                              size_t ws_size, hipStream_t stream) {
  const float* z = (const float*)d_in[0];
  const float* w = (const float*)d_in[1];
  float* out = (float*)d_out;
  double* loss_acc = (double*)d_ws;  // 8 bytes of ws only

  hipMemsetAsync(d_ws, 0, 8, stream);
  vq_main_k<<<N_TOK / 256, 256, 0, stream>>>(z, w, out, loss_acc);
  vq_final_k<<<1, 1, 0, stream>>>(loss_acc, out);
}

// Round 4
// 787.029 us; speedup vs baseline: 1.0503x; 1.0503x over previous
//
#include <hip/hip_runtime.h>

#define N_TOK 262144
#define DIM 64
#define K_CODES 1024
#define OUT_LOSS_OFF (N_TOK * DIM)      // 16777216
#define OUT_IDX_OFF (N_TOK * DIM + 1)   // 16777217

// Emulates np.sum(x**2) for 64 contiguous fp32 values: numpy pairwise
// summation (8 accumulators, unroll-8, then paired combine). Squares are
// individually rounded (contract OFF prevents x*x+r -> fma fusion).
__device__ __forceinline__ float np_sumsq64(const float* x) {
#pragma clang fp contract(off)
  float r[8];
#pragma unroll
  for (int j = 0; j < 8; ++j) r[j] = x[j] * x[j];
#pragma unroll
  for (int i = 8; i < 64; i += 8) {
#pragma unroll
    for (int j = 0; j < 8; ++j) r[j] += x[i + j] * x[i + j];
  }
  return ((r[0] + r[1]) + (r[2] + r[3])) + ((r[4] + r[5]) + (r[6] + r[7]));
}

// ---------------- main: one thread per token ----------------
// launch_bounds (256, 3): VGPR cap ~168 so zs[64] stays in registers.
// Round-3 ran with an implicit high-occupancy target -> VGPR_Count=56 ->
// the z row spilled to scratch (3.45x the FMA floor, WRITE_SIZE 16MB over).
__global__ __launch_bounds__(256, 3) void vq_main_k(
    const float* __restrict__ z, const float* __restrict__ w,
    float* __restrict__ out, double* __restrict__ loss_acc) {
#pragma clang fp contract(off)
  __shared__ float s_w2[K_CODES];
  __shared__ double red[4];

  // Block-cooperative ||w_c||^2 into LDS, numpy-pairwise bit-exact.
  for (int c0 = 0; c0 < K_CODES; c0 += 256) {
    int c = c0 + (int)threadIdx.x;
    float wl[DIM];
    const float4* wp = (const float4*)(w + (size_t)c * DIM);
#pragma unroll
    for (int i = 0; i < 16; ++i) {
      float4 v = wp[i];
      wl[4 * i + 0] = v.x;
      wl[4 * i + 1] = v.y;
      wl[4 * i + 2] = v.z;
      wl[4 * i + 3] = v.w;
    }
    s_w2[c] = np_sumsq64(wl);
  }
  __syncthreads();

  const int t = blockIdx.x * 256 + (int)threadIdx.x;

  // zs = 2*z resident in 64 VGPRs (doubling is exact; BLAS computed (2z)@wT).
  float zs[DIM];
  {
    const float4* zp = (const float4*)(z + (size_t)t * DIM);
#pragma unroll
    for (int i = 0; i < 16; ++i) {
      float4 v = zp[i];
      zs[4 * i + 0] = v.x + v.x;
      zs[4 * i + 1] = v.y + v.y;
      zs[4 * i + 2] = v.z + v.z;
      zs[4 * i + 3] = v.w + v.w;
    }
  }

  // ||z||^2, numpy-pairwise bit-exact (recover z = 0.5*zs exactly).
  float s_z2;
  {
    float zl[DIM];
#pragma unroll
    for (int k = 0; k < DIM; ++k) zl[k] = 0.5f * zs[k];
    s_z2 = np_sumsq64(zl);
  }

  // Main loop: emulate np's dist = fl(fl(s_z2 + s_w2[c]) - dot2[c]) where
  // dot2 = sequential-k fma chain of (2z_k)*w_k (BLAS sgemm microkernel
  // order). argmin with strict '<' = numpy first-min-wins.
  float best = 3.4e38f;
  int bidx = 0;
#pragma unroll 1
  for (int c = 0; c < K_CODES; c += 4) {
    const float4* w0 = (const float4*)(w + (size_t)c * DIM);
    const float4* w1 = (const float4*)(w + (size_t)(c + 1) * DIM);
    const float4* w2 = (const float4*)(w + (size_t)(c + 2) * DIM);
    const float4* w3 = (const float4*)(w + (size_t)(c + 3) * DIM);
    float a0 = 0.f, a1 = 0.f, a2 = 0.f, a3 = 0.f;
#pragma unroll
    for (int i = 0; i < 16; ++i) {
      float4 p0 = w0[i];
      float4 p1 = w1[i];
      float4 p2 = w2[i];
      float4 p3 = w3[i];
      // strictly ascending k within each chain (4 independent chains for ILP)
      a0 = __builtin_fmaf(zs[4 * i + 0], p0.x, a0);
      a0 = __builtin_fmaf(zs[4 * i + 1], p0.y, a0);
      a0 = __builtin_fmaf(zs[4 * i + 2], p0.z, a0);
      a0 = __builtin_fmaf(zs[4 * i + 3], p0.w, a0);
      a1 = __builtin_fmaf(zs[4 * i + 0], p1.x, a1);
      a1 = __builtin_fmaf(zs[4 * i + 1], p1.y, a1);
      a1 = __builtin_fmaf(zs[4 * i + 2], p1.z, a1);
      a1 = __builtin_fmaf(zs[4 * i + 3], p1.w, a1);
      a2 = __builtin_fmaf(zs[4 * i + 0], p2.x, a2);
      a2 = __builtin_fmaf(zs[4 * i + 1], p2.y, a2);
      a2 = __builtin_fmaf(zs[4 * i + 2], p2.z, a2);
      a2 = __builtin_fmaf(zs[4 * i + 3], p2.w, a2);
      a3 = __builtin_fmaf(zs[4 * i + 0], p3.x, a3);
      a3 = __builtin_fmaf(zs[4 * i + 1], p3.y, a3);
      a3 = __builtin_fmaf(zs[4 * i + 2], p3.z, a3);
      a3 = __builtin_fmaf(zs[4 * i + 3], p3.w, a3);
    }
    float d0 = (s_z2 + s_w2[c + 0]) - a0;  // two separately-rounded fp32 adds
    float d1 = (s_z2 + s_w2[c + 1]) - a1;
    float d2 = (s_z2 + s_w2[c + 2]) - a2;
    float d3 = (s_z2 + s_w2[c + 3]) - a3;
    if (d0 < best) { best = d0; bidx = c + 0; }
    if (d1 < best) { best = d1; bidx = c + 1; }
    if (d2 < best) { best = d2; bidx = c + 2; }
    if (d3 < best) { best = d3; bidx = c + 3; }
  }

  // Epilogue: write z_q (== z_q_st numerically within fp32 threshold), index,
  // and fp64 loss from the final index.
  double ls = 0.0;
  {
    const float4* wq = (const float4*)(w + (size_t)bidx * DIM);
    float4* op = (float4*)(out + (size_t)t * DIM);
#pragma unroll
    for (int i = 0; i < 16; ++i) {
      float4 v = wq[i];
      op[i] = v;
      double d0 = (double)v.x - 0.5 * (double)zs[4 * i + 0];
      double d1 = (double)v.y - 0.5 * (double)zs[4 * i + 1];
      double d2 = (double)v.z - 0.5 * (double)zs[4 * i + 2];
      double d3 = (double)v.w - 0.5 * (double)zs[4 * i + 3];
      ls = __builtin_fma(d0, d0, ls);
      ls = __builtin_fma(d1, d1, ls);
      ls = __builtin_fma(d2, d2, ls);
      ls = __builtin_fma(d3, d3, ls);
    }
  }
  out[OUT_IDX_OFF + t] = (float)bidx;

  // loss reduce: wave shuffle -> LDS -> one atomic per block
  for (int off = 32; off > 0; off >>= 1) ls += __shfl_down(ls, off, 64);
  if ((threadIdx.x & 63) == 0) red[threadIdx.x >> 6] = ls;
  __syncthreads();
  if (threadIdx.x == 0)
    atomicAdd(loss_acc, (red[0] + red[1]) + (red[2] + red[3]));
}

// ---------------- finalize loss ----------------
__global__ void vq_final_k(const double* __restrict__ loss_acc,
                           float* __restrict__ out) {
  // loss = q_latent + 0.25 * e_latent = 1.25 * mean((z_q - z)^2)
  out[OUT_LOSS_OFF] =
      (float)(1.25 * (*loss_acc) * (1.0 / (double)((size_t)N_TOK * DIM)));
}

extern "C" void kernel_launch(void* const* d_in, const int* in_sizes, int n_in,
                              void* d_out, int out_size, void* d_ws,
                              size_t ws_size, hipStream_t stream) {
  const float* z = (const float*)d_in[0];
  const float* w = (const float*)d_in[1];
  float* out = (float*)d_out;
  double* loss_acc = (double*)d_ws;  // 8 bytes of ws only

  hipMemsetAsync(d_ws, 0, 8, stream);
  vq_main_k<<<N_TOK / 256, 256, 0, stream>>>(z, w, out, loss_acc);
  vq_final_k<<<1, 1, 0, stream>>>(loss_acc, out);
}